// Round 8
// baseline (646.541 us; speedup 1.0000x reference)
//
#include <hip/hip_runtime.h>
#include <hip/hip_bf16.h>

typedef __hip_bfloat16 bf16;
typedef __attribute__((ext_vector_type(8)))  short bf16x8v;  // 8 bf16 (4 VGPRs) MFMA operand
typedef __attribute__((ext_vector_type(16))) float f32x16;   // 32x32 MFMA accumulator
typedef __attribute__((ext_vector_type(4)))  short short4v;  // 8B packed bf16 store

#define B_SZ   2048
#define NSTEP  128
#define DD     100
#define DX     100
#define DH     256

#define UCOLS  104          // 100 x-dims + t + 3 zero pad (global U layout)

__device__ __constant__ const float DT_   = 0.0078125f;              // 1/128
__device__ __constant__ const float SQDT_ = 0.08838834764831845f;    // sqrt(1/128)
// sqrt(2)*sqrt(dt) = sqrt(2/128) = 1/8 exactly
__device__ __constant__ const float C1_   = 0.125f;

// ---------------------------------------------------------------------------
// Kernel 1: per-batch prefix sums of noise -> build U rows (bf16) + final x
// U row p = (b*128 + i)*2 + h ; cols 0..99 = x-part, col 100 = t, 101..103 = 0
// ---------------------------------------------------------------------------
__global__ __launch_bounds__(128) void prep_kernel(
    const float* __restrict__ Wn, const int* __restrict__ signs,
    const float* __restrict__ x0,
    bf16* __restrict__ U, float* __restrict__ xout)
{
    __shared__ float w_l[DD * 129];   // padded stride 129 -> conflict-free
    __shared__ float s_l[NSTEP];
    const int b = blockIdx.x, tid = threadIdx.x;
    const float* wb = Wn + (size_t)b * DD * NSTEP;

    for (int idx = tid; idx < DD * NSTEP; idx += 128) {
        int d = idx >> 7, i = idx & 127;
        w_l[d * 129 + i] = wb[idx];
    }
    if (tid < NSTEP) s_l[tid] = 2.f * (float)signs[tid] - 1.f;
    __syncthreads();

    if (tid < DD) {
        const int d = tid;
        float x = x0[d];
        for (int i = 0; i < NSTEP; ++i) {
            size_t p = ((size_t)(b * NSTEP + i)) * 2;
            float wn = w_l[d * 129 + i];
            U[p * UCOLS + d]       = __float2bfloat16(x);
            U[(p + 1) * UCOLS + d] = __float2bfloat16(x + C1_ * (wn - s_l[i]));
            x += C1_ * wn;
        }
        xout[(size_t)b * DX + d] = x;   // exact f32 final x
    } else if (tid < UCOLS) {
        for (int i = 0; i < NSTEP; ++i) {
            size_t p = ((size_t)(b * NSTEP + i)) * 2;
            float v0 = 0.f, v1 = 0.f;
            if (tid == 100) { v0 = DT_ * (float)i; v1 = DT_ * (float)(i + 1); }
            U[p * UCOLS + tid]       = __float2bfloat16(v0);
            U[(p + 1) * UCOLS + tid] = __float2bfloat16(v1);
        }
    }
}

// ---------------------------------------------------------------------------
// Weight fragment packing for 32x32x16 MFMA (unchanged from R7, proven):
// c-major: frag# = c*NTILE + t. elem idx = frag#*512 + lane*8 + j.
// n = t*32 + (lane&31), k = c*16 + (lane>>5)*8 + j. OOR -> 0.
// ---------------------------------------------------------------------------
__global__ __launch_bounds__(256) void wpack_kernel(
    const float* __restrict__ W, bf16* __restrict__ dst,
    int Kact, int Nact, int NTILE, int total)
{
    int idx = blockIdx.x * 256 + threadIdx.x;
    if (idx >= total) return;
    int j = idx & 7;
    int l = (idx >> 3) & 63;
    int frag = idx >> 9;
    int t = frag % NTILE;
    int c = frag / NTILE;
    int n = t * 32 + (l & 31);
    int k = c * 16 + (l >> 5) * 8 + j;
    float v = (k < Kact && n < Nact) ? W[(size_t)k * Nact + n] : 0.f;
    dst[idx] = __float2bfloat16(v);
}

// Pack biases into one padded f32 buffer: [0:256)=bi [256:512)=bh1 [512:768)=bh2 [768:896)=bo(pad0)
__global__ __launch_bounds__(256) void bpack_kernel(
    const float* __restrict__ bi, const float* __restrict__ bh1,
    const float* __restrict__ bh2, const float* __restrict__ bo,
    float* __restrict__ dst)
{
    int i = blockIdx.x * 256 + threadIdx.x;
    if (i < 256) dst[i] = bi[i];
    else if (i < 512) dst[i] = bh1[i - 256];
    else if (i < 768) dst[i] = bh2[i - 512];
    else if (i < 896) dst[i] = (i - 768 < DD) ? bo[i - 768] : 0.f;
}

// ---------------------------------------------------------------------------
// Accumulate chunk: c-iters [C0,C1) of a 32x32x16 layer into acc (NT n-tiles,
// 2 m-tiles of the 64-row tile in bufR). Static bounds, R7-proven math.
// ---------------------------------------------------------------------------
template<int C0, int C1, int NTT, int NT, bool INIT>
__device__ __forceinline__ void acc_chunk(
    const char* __restrict__ bufR, const bf16* __restrict__ wfrag,
    f32x16 (&acc)[2][2], int lane, int t0)
{
    const int mrow = lane & 31, kg = lane >> 5;
    if (INIT) {
#pragma unroll
        for (int t = 0; t < NT; ++t)
#pragma unroll
            for (int mt = 0; mt < 2; ++mt)
#pragma unroll
                for (int e = 0; e < 16; ++e) acc[t][mt][e] = 0.f;
    }
    const char* wptr = (const char*)wfrag + (size_t)t0 * 1024 + (size_t)lane * 16;
#pragma unroll
    for (int c = C0; c < C1; ++c) {
        const int col = c * 32 + kg * 16;
        const int ma = mrow, mb = 32 + mrow;
        bf16x8v b0 = *(const bf16x8v*)(bufR + ma * 512 + (col ^ ((ma & 15) << 4)));
        bf16x8v b1 = *(const bf16x8v*)(bufR + mb * 512 + (col ^ ((mb & 15) << 4)));
        __builtin_amdgcn_s_setprio(1);
#pragma unroll
        for (int t = 0; t < NT; ++t) {
            bf16x8v a = *(const bf16x8v*)(wptr + (size_t)(c * NTT + t) * 1024);
            acc[t][0] = __builtin_amdgcn_mfma_f32_32x32x16_bf16(a, b0, acc[t][0], 0, 0, 0);
            acc[t][1] = __builtin_amdgcn_mfma_f32_32x32x16_bf16(a, b1, acc[t][1], 0, 0, 0);
        }
        __builtin_amdgcn_s_setprio(0);
    }
}

// ---------------------------------------------------------------------------
// Epilogue chunk: steps [S0,S1) of bias+relu+pack+store for an acc holding
// ENT n-tiles. Step s -> t=s>>3, g=(s>>1)&3, mt=s&1 (all static under unroll).
// C/D layout 32x32: col(m)=lane&31, row(n)=(r&3)+8*(r>>2)+4*kg.
// ---------------------------------------------------------------------------
template<int S0, int S1, int ENT, bool ERELU>
__device__ __forceinline__ void epi_chunk(
    char* __restrict__ bufW, const float* __restrict__ eb,
    f32x16 (&acc)[2][2], int lane, int t0)
{
    const int mrow = lane & 31, kg = lane >> 5;
#pragma unroll
    for (int s = S0; s < S1; ++s) {
        const int t = s >> 3, g = (s >> 1) & 3, mt = s & 1;
        const int nb = (t0 + t) * 32 + g * 8 + kg * 4;
        const float4 bv = *(const float4*)(eb + nb);
        const int m = mt * 32 + mrow;
        float v0 = acc[t][mt][g * 4 + 0] + bv.x;
        float v1 = acc[t][mt][g * 4 + 1] + bv.y;
        float v2 = acc[t][mt][g * 4 + 2] + bv.z;
        float v3 = acc[t][mt][g * 4 + 3] + bv.w;
        if (ERELU) {
            v0 = fmaxf(v0, 0.f); v1 = fmaxf(v1, 0.f);
            v2 = fmaxf(v2, 0.f); v3 = fmaxf(v3, 0.f);
        }
        bf16 h0 = __float2bfloat16(v0), h1 = __float2bfloat16(v1);
        bf16 h2 = __float2bfloat16(v2), h3 = __float2bfloat16(v3);
        short4v pv;
        pv[0] = *(short*)&h0; pv[1] = *(short*)&h1;
        pv[2] = *(short*)&h2; pv[3] = *(short*)&h3;
        *(short4v*)(bufW + m * 512 + ((nb * 2) ^ ((m & 15) << 4))) = pv;
    }
}

// ---------------------------------------------------------------------------
// Mixed phase: accumulate (bufR -> aN) interleaved IN PROGRAM ORDER with the
// epilogue of the other tile's previous layer (aO -> bufW), at 1/4 granularity.
// This is the deterministic MFMA/VALU overlap the phase-locked blocks never
// gave us (R3..R7: pipes ~serialized; MFMA+VALU+LDS summed to the wall).
// ---------------------------------------------------------------------------
template<int KC, int NTT, int NT, int ENT, bool ERELU>
__device__ __forceinline__ void mixed_phase(
    const char* __restrict__ bufR, char* __restrict__ bufW,
    const bf16* __restrict__ wf, const float* __restrict__ eb,
    f32x16 (&aN)[2][2], f32x16 (&aO)[2][2],
    int lane, int t0n, int t0o)
{
    constexpr int Q1 = KC / 4, Q2 = KC / 2, Q3 = (3 * KC) / 4;
    constexpr int E  = ENT * 8;
    constexpr int E1 = E / 4, E2 = E / 2, E3 = (3 * E) / 4;
    acc_chunk<0,  Q1, NTT, NT, true >(bufR, wf, aN, lane, t0n);
    epi_chunk<0,  E1, ENT, ERELU>(bufW, eb, aO, lane, t0o);
    acc_chunk<Q1, Q2, NTT, NT, false>(bufR, wf, aN, lane, t0n);
    epi_chunk<E1, E2, ENT, ERELU>(bufW, eb, aO, lane, t0o);
    acc_chunk<Q2, Q3, NTT, NT, false>(bufR, wf, aN, lane, t0n);
    epi_chunk<E2, E3, ENT, ERELU>(bufW, eb, aO, lane, t0o);
    acc_chunk<Q3, KC, NTT, NT, false>(bufR, wf, aN, lane, t0n);
    epi_chunk<E3, E,  ENT, ERELU>(bufW, eb, aO, lane, t0o);
}

// ---------------------------------------------------------------------------
// Per-tile reduction, LDS-array-free: 4 threads/row, shuffle-combined; pair
// partner row via shfl_xor(4) (rows adjacent in tid-space within the wave).
// ---------------------------------------------------------------------------
__device__ __forceinline__ void reduce_tile(
    const char* __restrict__ buf, const float* __restrict__ Wn,
    const int* __restrict__ signs, float* __restrict__ incr,
    size_t row0t, int tid)
{
    const int r = tid >> 2, q = tid & 3;
    const size_t g = row0t + r;
    const size_t pair = g >> 1;
    const int h = (int)(g & 1);
    const int bb = (int)(pair >> 7), ii = (int)(pair & 127);
    const float s = 2.f * (float)signs[ii] - 1.f;
    const float sdt = s * SQDT_;
    const float* wb = Wn + (size_t)bb * DD * NSTEP + ii;

    float sz2 = 0.f, szw = 0.f;
    for (int d = q; d < DD; d += 4) {
        unsigned short zb = *(const unsigned short*)(buf + r * 512 + ((d * 2) ^ ((r & 15) << 4)));
        union { unsigned int u; float f; } cv; cv.u = ((unsigned int)zb) << 16;
        float z = cv.f;
        float wv = SQDT_ * wb[(size_t)d * NSTEP];
        float wt = h ? (wv + sdt) : (wv - sdt);
        sz2 += z * z;
        szw += z * wt;
    }
    sz2 += __shfl_xor(sz2, 1); sz2 += __shfl_xor(sz2, 2);
    szw += __shfl_xor(szw, 1); szw += __shfl_xor(szw, 2);
    float szw_o = __shfl_xor(szw, 4);   // partner row's szw
    if ((tid & 7) == 0) {               // q==0 and r even (h=0 row)
        incr[(row0t >> 1) + (r >> 1)] = -sz2 * DT_ + 0.5f * (szw + szw_o);
    }
}

// ---------------------------------------------------------------------------
// Kernel 2: two 64-row tiles per block, ping-pong buffers, phases interleave
// accum(tile X) with epilogue(tile Y) deterministically.
// LDS 64KB -> 2 blocks/CU. acc 2x64 = 128 regs + arch -> (256,2), cap 256
// (tripwire: WRITE_SIZE ~1MB; R1/R4 died of spill). Weights 1x per 128 rows.
// ---------------------------------------------------------------------------
__global__ __launch_bounds__(256, 2) void mlp_mfma_kernel(
    const bf16* __restrict__ U,
    const float* __restrict__ Wn, const int* __restrict__ signs,
    const bf16* __restrict__ wfWi, const bf16* __restrict__ wfWh1,
    const bf16* __restrict__ wfWh2, const bf16* __restrict__ wfWo,
    const float* __restrict__ biases, float* __restrict__ incr)
{
    __shared__ char buf0[64 * 512];
    __shared__ char buf1[64 * 512];
    const int tid = threadIdx.x;
    const int lane = tid & 63, w = tid >> 6;
    const size_t row0 = (size_t)blockIdx.x * 128;

    f32x16 accA[2][2], accB[2][2];

    // Stage U: rows 0-63 -> buf0, 64-127 -> buf1. 13 x 16B chunks/row,
    // chunks 13..15 zero-filled (k-padding must be 0). Swizzle (m&15)<<4.
    {
        const char* usrc = (const char*)(U + row0 * UCOLS);
        for (int idx = tid; idx < 2048; idx += 256) {
            int r = idx >> 4, c = idx & 15;
            uint4 v = (uint4){0, 0, 0, 0};
            if (c < 13) v = *(const uint4*)(usrc + r * 208 + c * 16);
            char* bb = (r < 64) ? buf0 : buf1;
            int m = r & 63;
            *(uint4*)(bb + m * 512 + ((c * 16) ^ ((m & 15) << 4))) = v;
        }
    }
    __syncthreads();

    // P0: accum A = L1(T0)
    acc_chunk<0, 7, 8, 2, true>(buf0, wfWi, accA, lane, w * 2);
    __syncthreads();
    // P1: accum B = L1(T1)  ||  epi A (L1 out) -> buf0
    mixed_phase<7, 8, 2, 2, true>(buf1, buf0, wfWi, biases, accB, accA, lane, w * 2, w * 2);
    __syncthreads();
    // P2: accum A = L2(T0)  ||  epi B (L1 out) -> buf1
    mixed_phase<16, 8, 2, 2, true>(buf0, buf1, wfWh1, biases, accA, accB, lane, w * 2, w * 2);
    __syncthreads();
    // P3: accum B = L2(T1)  ||  epi A (L2 out) -> buf0
    mixed_phase<16, 8, 2, 2, true>(buf1, buf0, wfWh1, biases + 256, accB, accA, lane, w * 2, w * 2);
    __syncthreads();
    // P4: accum A = L3(T0)  ||  epi B (L2 out) -> buf1
    mixed_phase<16, 8, 2, 2, true>(buf0, buf1, wfWh2, biases + 256, accA, accB, lane, w * 2, w * 2);
    __syncthreads();
    // P5: accum B = L3(T1)  ||  epi A (L3 out) -> buf0
    mixed_phase<16, 8, 2, 2, true>(buf1, buf0, wfWh2, biases + 512, accB, accA, lane, w * 2, w * 2);
    __syncthreads();
    // P6: accum A = L4(T0)  ||  epi B (L3 out) -> buf1
    mixed_phase<16, 4, 1, 2, true>(buf0, buf1, wfWo, biases + 512, accA, accB, lane, w, w * 2);
    __syncthreads();
    // P7: accum B = L4(T1)  ||  epi A (L4 out, no relu) -> buf0
    mixed_phase<16, 4, 1, 1, false>(buf1, buf0, wfWo, biases + 768, accB, accA, lane, w, w);
    __syncthreads();
    // P8: epi B (L4 out) -> buf1  ||  reduction T0 (buf0)
    epi_chunk<0, 8, 1, false>(buf1, biases + 768, accB, lane, w);
    reduce_tile(buf0, Wn, signs, incr, row0, tid);
    __syncthreads();
    // P9: reduction T1 (buf1)
    reduce_tile(buf1, Wn, signs, incr, row0 + 64, tid);
}

// ---------------------------------------------------------------------------
// Kernel 3: y[b] = y0 + sum_i incr[b*128+i]
// ---------------------------------------------------------------------------
__global__ __launch_bounds__(128) void y_kernel(
    const float* __restrict__ incr, const float* __restrict__ y0,
    float* __restrict__ yout)
{
    const int b = blockIdx.x, tid = threadIdx.x;
    float v = incr[(size_t)b * NSTEP + tid];
#pragma unroll
    for (int off = 1; off < 64; off <<= 1) v += __shfl_xor(v, off);
    __shared__ float partial[2];
    if ((tid & 63) == 0) partial[tid >> 6] = v;
    __syncthreads();
    if (tid == 0) yout[b] = y0[0] + partial[0] + partial[1];
}

// ---------------------------------------------------------------------------
extern "C" void kernel_launch(void* const* d_in, const int* in_sizes, int n_in,
                              void* d_out, int out_size, void* d_ws, size_t ws_size,
                              hipStream_t stream) {
    (void)in_sizes; (void)n_in; (void)out_size; (void)ws_size;
    const float* Wn    = (const float*)d_in[0];
    const int*   signs = (const int*)d_in[1];
    const float* x0    = (const float*)d_in[2];
    const float* y0    = (const float*)d_in[3];
    const float* Wi    = (const float*)d_in[4];
    const float* bi    = (const float*)d_in[5];
    const float* Wh1   = (const float*)d_in[6];
    const float* bh1   = (const float*)d_in[7];
    const float* Wh2   = (const float*)d_in[8];
    const float* bh2   = (const float*)d_in[9];
    const float* Wo    = (const float*)d_in[10];
    const float* bo    = (const float*)d_in[11];

    float* out  = (float*)d_out;
    float* xout = out;                       // [2048,100]
    float* yout = out + (size_t)B_SZ * DX;   // [2048,1]

    const size_t NROWS = (size_t)B_SZ * NSTEP * 2;           // 524288
    char* ws = (char*)d_ws;
    size_t off = 0;
    bf16*  U      = (bf16*)(ws + off); off += NROWS * UCOLS * sizeof(bf16);   // ~109 MB
    float* incr   = (float*)(ws + off); off += (NROWS / 2) * sizeof(float);   // 1 MB
    bf16*  wfWi   = (bf16*)(ws + off); off += 28672 * sizeof(bf16);   // KC=7,  8 tiles
    bf16*  wfWh1  = (bf16*)(ws + off); off += 65536 * sizeof(bf16);   // KC=16, 8 tiles
    bf16*  wfWh2  = (bf16*)(ws + off); off += 65536 * sizeof(bf16);
    bf16*  wfWo   = (bf16*)(ws + off); off += 32768 * sizeof(bf16);   // KC=16, 4 tiles
    float* biases = (float*)(ws + off); off += 896 * sizeof(float);

    prep_kernel<<<B_SZ, 128, 0, stream>>>(Wn, signs, x0, U, xout);
    // c-major 32x32 frag layout: NTILE = n-tiles of 32
    wpack_kernel<<<112, 256, 0, stream>>>(Wi,  wfWi,  101, 256, 8, 28672);
    wpack_kernel<<<256, 256, 0, stream>>>(Wh1, wfWh1, 256, 256, 8, 65536);
    wpack_kernel<<<256, 256, 0, stream>>>(Wh2, wfWh2, 256, 256, 8, 65536);
    wpack_kernel<<<128, 256, 0, stream>>>(Wo,  wfWo,  256, 100, 4, 32768);
    bpack_kernel<<<4, 256, 0, stream>>>(bi, bh1, bh2, bo, biases);

    mlp_mfma_kernel<<<(int)(NROWS / 128), 256, 0, stream>>>(
        U, Wn, signs, wfWi, wfWh1, wfWh2, wfWo, biases, incr);
    y_kernel<<<B_SZ, 128, 0, stream>>>(incr, y0, yout);
}

// Round 9
// 377.746 us; speedup vs baseline: 1.7116x; 1.7116x over previous
//
#include <hip/hip_runtime.h>
#include <hip/hip_bf16.h>

typedef __hip_bfloat16 bf16;
typedef __attribute__((ext_vector_type(8)))  short bf16x8v;  // 8 bf16 (4 VGPRs) MFMA operand
typedef __attribute__((ext_vector_type(16))) float f32x16;   // 32x32 MFMA accumulator
typedef __attribute__((ext_vector_type(4)))  short short4v;  // 8B packed bf16 store

#define B_SZ   2048
#define NSTEP  128
#define DD     100
#define DX     100
#define DH     256

#define UCOLS  104          // 100 x-dims + t + 3 zero pad (global U layout)

__device__ __constant__ const float DT_   = 0.0078125f;              // 1/128
__device__ __constant__ const float SQDT_ = 0.08838834764831845f;    // sqrt(1/128)
// sqrt(2)*sqrt(dt) = sqrt(2/128) = 1/8 exactly
__device__ __constant__ const float C1_   = 0.125f;

// ---------------------------------------------------------------------------
// Kernel 1: per-batch prefix sums of noise -> build U rows (bf16) + final x
// U row p = (b*128 + i)*2 + h ; cols 0..99 = x-part, col 100 = t, 101..103 = 0
// ---------------------------------------------------------------------------
__global__ __launch_bounds__(128) void prep_kernel(
    const float* __restrict__ Wn, const int* __restrict__ signs,
    const float* __restrict__ x0,
    bf16* __restrict__ U, float* __restrict__ xout)
{
    __shared__ float w_l[DD * 129];   // padded stride 129 -> conflict-free
    __shared__ float s_l[NSTEP];
    const int b = blockIdx.x, tid = threadIdx.x;
    const float* wb = Wn + (size_t)b * DD * NSTEP;

    for (int idx = tid; idx < DD * NSTEP; idx += 128) {
        int d = idx >> 7, i = idx & 127;
        w_l[d * 129 + i] = wb[idx];
    }
    if (tid < NSTEP) s_l[tid] = 2.f * (float)signs[tid] - 1.f;
    __syncthreads();

    if (tid < DD) {
        const int d = tid;
        float x = x0[d];
        for (int i = 0; i < NSTEP; ++i) {
            size_t p = ((size_t)(b * NSTEP + i)) * 2;
            float wn = w_l[d * 129 + i];
            U[p * UCOLS + d]       = __float2bfloat16(x);
            U[(p + 1) * UCOLS + d] = __float2bfloat16(x + C1_ * (wn - s_l[i]));
            x += C1_ * wn;
        }
        xout[(size_t)b * DX + d] = x;   // exact f32 final x
    } else if (tid < UCOLS) {
        for (int i = 0; i < NSTEP; ++i) {
            size_t p = ((size_t)(b * NSTEP + i)) * 2;
            float v0 = 0.f, v1 = 0.f;
            if (tid == 100) { v0 = DT_ * (float)i; v1 = DT_ * (float)(i + 1); }
            U[p * UCOLS + tid]       = __float2bfloat16(v0);
            U[(p + 1) * UCOLS + tid] = __float2bfloat16(v1);
        }
    }
}

// ---------------------------------------------------------------------------
// Weight fragment packing for 32x32x16 MFMA (R7-proven):
// c-major: frag# = c*NTILE + t. elem idx = frag#*512 + lane*8 + j.
// n = t*32 + (lane&31), k = c*16 + (lane>>5)*8 + j. OOR -> 0.
// ---------------------------------------------------------------------------
__global__ __launch_bounds__(256) void wpack_kernel(
    const float* __restrict__ W, bf16* __restrict__ dst,
    int Kact, int Nact, int NTILE, int total)
{
    int idx = blockIdx.x * 256 + threadIdx.x;
    if (idx >= total) return;
    int j = idx & 7;
    int l = (idx >> 3) & 63;
    int frag = idx >> 9;
    int t = frag % NTILE;
    int c = frag / NTILE;
    int n = t * 32 + (l & 31);
    int k = c * 16 + (l >> 5) * 8 + j;
    float v = (k < Kact && n < Nact) ? W[(size_t)k * Nact + n] : 0.f;
    dst[idx] = __float2bfloat16(v);
}

// Pack biases into one padded f32 buffer: [0:256)=bi [256:512)=bh1 [512:768)=bh2 [768:896)=bo(pad0)
__global__ __launch_bounds__(256) void bpack_kernel(
    const float* __restrict__ bi, const float* __restrict__ bh1,
    const float* __restrict__ bh2, const float* __restrict__ bo,
    float* __restrict__ dst)
{
    int i = blockIdx.x * 256 + threadIdx.x;
    if (i < 256) dst[i] = bi[i];
    else if (i < 512) dst[i] = bh1[i - 256];
    else if (i < 768) dst[i] = bh2[i - 512];
    else if (i < 896) dst[i] = (i - 768 < DD) ? bo[i - 768] : 0.f;
}

// ---------------------------------------------------------------------------
// One 32x32x16-MFMA layer, IN PLACE, 128-row tile, 4-way n-split.
// Combines the two proven wins: 32x32 (R7: half the instructions, clean regs)
// + 128-row tile (R3: weight-L2 traffic per row halves, 8 MFMAs per c-iter
// cover each a-load pair). Wave w owns NT n-tiles at t0; all 128 rows
// (MT=4 m-tiles of 32). ONE acc set live (R8 lesson: two live sets spill).
// Per c-iter: MT ds_read_b128 + NT a-loads + NT*MT MFMAs (8 for NT=2).
//   phase 1: accumulate into regs -> __syncthreads
//   phase 2: bias+relu+pack, store back to buf
// Caller must __syncthreads() after return before the next layer reads.
// Swizzle: byte ^= (m&15)<<4 (R7-proven, bijective within 256B half-row).
// ---------------------------------------------------------------------------
template<int KC, int NTT, int NT, int MT, bool RELU>
__device__ __forceinline__ void layer32(
    char* __restrict__ buf,
    const bf16* __restrict__ wfrag, const float* __restrict__ bias,
    int lane, int t0)
{
    const int mrow = lane & 31;   // m within tile (B col)
    const int kg   = lane >> 5;   // k-group (0/1)
    f32x16 acc[NT][MT];
#pragma unroll
    for (int t = 0; t < NT; ++t)
#pragma unroll
        for (int mt = 0; mt < MT; ++mt)
#pragma unroll
            for (int e = 0; e < 16; ++e) acc[t][mt][e] = 0.f;

    const char* wptr = (const char*)wfrag + (size_t)t0 * 1024 + (size_t)lane * 16;

#pragma unroll 2
    for (int c = 0; c < KC; ++c) {
        const int col = c * 32 + kg * 16;
        bf16x8v b[MT];
#pragma unroll
        for (int mt = 0; mt < MT; ++mt) {
            const int m = mt * 32 + mrow;
            b[mt] = *(const bf16x8v*)(buf + m * 512 + (col ^ ((m & 15) << 4)));
        }
        __builtin_amdgcn_s_setprio(1);
#pragma unroll
        for (int t = 0; t < NT; ++t) {
            bf16x8v a = *(const bf16x8v*)(wptr + (size_t)(c * NTT + t) * 1024);
#pragma unroll
            for (int mt = 0; mt < MT; ++mt)
                acc[t][mt] = __builtin_amdgcn_mfma_f32_32x32x16_bf16(a, b[mt], acc[t][mt], 0, 0, 0);
        }
        __builtin_amdgcn_s_setprio(0);
    }

    __syncthreads();   // all reads of buf complete block-wide; safe to overwrite

    // C/D layout 32x32: col(m) = lane&31, row(n) = (r&3) + 8*(r>>2) + 4*kg
#pragma unroll
    for (int t = 0; t < NT; ++t) {
#pragma unroll
        for (int g = 0; g < 4; ++g) {
            const int nb = (t0 + t) * 32 + g * 8 + kg * 4;  // 4 consecutive features
            const float4 bv = *(const float4*)(bias + nb);
#pragma unroll
            for (int mt = 0; mt < MT; ++mt) {
                const int m = mt * 32 + mrow;
                float v0 = acc[t][mt][g * 4 + 0] + bv.x;
                float v1 = acc[t][mt][g * 4 + 1] + bv.y;
                float v2 = acc[t][mt][g * 4 + 2] + bv.z;
                float v3 = acc[t][mt][g * 4 + 3] + bv.w;
                if (RELU) {
                    v0 = fmaxf(v0, 0.f); v1 = fmaxf(v1, 0.f);
                    v2 = fmaxf(v2, 0.f); v3 = fmaxf(v3, 0.f);
                }
                bf16 h0 = __float2bfloat16(v0), h1 = __float2bfloat16(v1);
                bf16 h2 = __float2bfloat16(v2), h3 = __float2bfloat16(v3);
                short4v pv;
                pv[0] = *(short*)&h0; pv[1] = *(short*)&h1;
                pv[2] = *(short*)&h2; pv[3] = *(short*)&h3;
                *(short4v*)(buf + m * 512 + ((nb * 2) ^ ((m & 15) << 4))) = pv;
            }
        }
    }
}

// ---------------------------------------------------------------------------
// Kernel 2: fused 4-layer 32x32-MFMA MLP over 128 rows + per-pair y-increment.
// 4 waves n-split (weights 1x per 128 rows: L2 floor 89->45us vs 64-row).
// acc[2][4] = 128 AGPRs, ONE set live; arch ~90-110 -> (256,2) no spill
// (tripwire: WRITE_SIZE ~1MB, else round void). buf 64KB -> 2 blocks/CU.
// ---------------------------------------------------------------------------
__global__ __launch_bounds__(256, 2) void mlp_mfma_kernel(
    const bf16* __restrict__ U,
    const float* __restrict__ Wn, const int* __restrict__ signs,
    const bf16* __restrict__ wfWi, const bf16* __restrict__ wfWh1,
    const bf16* __restrict__ wfWh2, const bf16* __restrict__ wfWo,
    const float* __restrict__ biases, float* __restrict__ incr)
{
    __shared__ char buf[128 * 512];
    __shared__ float Sz2[128], Szw[128];
    const int tid = threadIdx.x;
    const int lane = tid & 63, w = tid >> 6;
    const size_t row0 = (size_t)blockIdx.x * 128;

    // Load U tile: 128 rows x 104 bf16 = 13 x 16B chunks/row -> buf [128][512B]
    // (layer-1 input occupies bytes 0..207, zero-fill to 255), swizzled.
    {
        const char* usrc = (const char*)(U + row0 * UCOLS);
        for (int idx = tid; idx < 2048; idx += 256) {
            int r = idx >> 4, c = idx & 15;
            uint4 v = (uint4){0, 0, 0, 0};
            if (c < 13) v = *(const uint4*)(usrc + r * 208 + c * 16);
            *(uint4*)(buf + r * 512 + ((c * 16) ^ ((r & 15) << 4))) = v;
        }
    }
    __syncthreads();

    layer32<7,  8, 2, 4, true >(buf, wfWi,  biases,        lane, w * 2);
    __syncthreads();
    layer32<16, 8, 2, 4, true >(buf, wfWh1, biases + 256,  lane, w * 2);
    __syncthreads();
    layer32<16, 8, 2, 4, true >(buf, wfWh2, biases + 512,  lane, w * 2);
    __syncthreads();
    layer32<16, 4, 1, 4, false>(buf, wfWo,  biases + 768,  lane, w);
    __syncthreads();
    // z rows now in buf [128][512B] (features 0..99 valid)

    // Per-row reductions: 4 threads per row, two passes of 64 rows
    const int q = tid & 3;
#pragma unroll
    for (int half = 0; half < 2; ++half) {
        const int r = (tid >> 2) + half * 64;
        const size_t g = row0 + r;
        const size_t pair = g >> 1;
        const int h = (int)(g & 1);
        const int bb = (int)(pair >> 7), ii = (int)(pair & 127);
        const float s = 2.f * (float)signs[ii] - 1.f;
        const float sdt = s * SQDT_;
        const float* wb = Wn + (size_t)bb * DD * NSTEP + ii;

        float sz2 = 0.f, szw = 0.f;
        for (int d = q; d < DD; d += 4) {
            unsigned short zb = *(const unsigned short*)(buf + r * 512 + ((d * 2) ^ ((r & 15) << 4)));
            union { unsigned int u; float f; } cv; cv.u = ((unsigned int)zb) << 16;
            float z = cv.f;
            float wv = SQDT_ * wb[(size_t)d * NSTEP];
            float wt = h ? (wv + sdt) : (wv - sdt);
            sz2 += z * z;
            szw += z * wt;
        }
        sz2 += __shfl_xor(sz2, 1); sz2 += __shfl_xor(sz2, 2);
        szw += __shfl_xor(szw, 1); szw += __shfl_xor(szw, 2);
        if (q == 0) { Sz2[r] = sz2; Szw[r] = szw; }
    }
    __syncthreads();

    // incr = -||z||^2*dt + 0.5*(z.(w-sdt) + z_new.(w+sdt));  z from h=0 row
    if (tid < 64) {
        int rr = tid * 2;
        incr[row0 / 2 + tid] = -Sz2[rr] * DT_ + 0.5f * (Szw[rr] + Szw[rr + 1]);
    }
}

// ---------------------------------------------------------------------------
// Kernel 3: y[b] = y0 + sum_i incr[b*128+i]
// ---------------------------------------------------------------------------
__global__ __launch_bounds__(128) void y_kernel(
    const float* __restrict__ incr, const float* __restrict__ y0,
    float* __restrict__ yout)
{
    const int b = blockIdx.x, tid = threadIdx.x;
    float v = incr[(size_t)b * NSTEP + tid];
#pragma unroll
    for (int off = 1; off < 64; off <<= 1) v += __shfl_xor(v, off);
    __shared__ float partial[2];
    if ((tid & 63) == 0) partial[tid >> 6] = v;
    __syncthreads();
    if (tid == 0) yout[b] = y0[0] + partial[0] + partial[1];
}

// ---------------------------------------------------------------------------
extern "C" void kernel_launch(void* const* d_in, const int* in_sizes, int n_in,
                              void* d_out, int out_size, void* d_ws, size_t ws_size,
                              hipStream_t stream) {
    (void)in_sizes; (void)n_in; (void)out_size; (void)ws_size;
    const float* Wn    = (const float*)d_in[0];
    const int*   signs = (const int*)d_in[1];
    const float* x0    = (const float*)d_in[2];
    const float* y0    = (const float*)d_in[3];
    const float* Wi    = (const float*)d_in[4];
    const float* bi    = (const float*)d_in[5];
    const float* Wh1   = (const float*)d_in[6];
    const float* bh1   = (const float*)d_in[7];
    const float* Wh2   = (const float*)d_in[8];
    const float* bh2   = (const float*)d_in[9];
    const float* Wo    = (const float*)d_in[10];
    const float* bo    = (const float*)d_in[11];

    float* out  = (float*)d_out;
    float* xout = out;                       // [2048,100]
    float* yout = out + (size_t)B_SZ * DX;   // [2048,1]

    const size_t NROWS = (size_t)B_SZ * NSTEP * 2;           // 524288
    char* ws = (char*)d_ws;
    size_t off = 0;
    bf16*  U      = (bf16*)(ws + off); off += NROWS * UCOLS * sizeof(bf16);   // ~109 MB
    float* incr   = (float*)(ws + off); off += (NROWS / 2) * sizeof(float);   // 1 MB
    bf16*  wfWi   = (bf16*)(ws + off); off += 28672 * sizeof(bf16);   // KC=7,  8 tiles
    bf16*  wfWh1  = (bf16*)(ws + off); off += 65536 * sizeof(bf16);   // KC=16, 8 tiles
    bf16*  wfWh2  = (bf16*)(ws + off); off += 65536 * sizeof(bf16);
    bf16*  wfWo   = (bf16*)(ws + off); off += 32768 * sizeof(bf16);   // KC=16, 4 tiles
    float* biases = (float*)(ws + off); off += 896 * sizeof(float);

    prep_kernel<<<B_SZ, 128, 0, stream>>>(Wn, signs, x0, U, xout);
    // c-major 32x32 frag layout: NTILE = n-tiles of 32
    wpack_kernel<<<112, 256, 0, stream>>>(Wi,  wfWi,  101, 256, 8, 28672);
    wpack_kernel<<<256, 256, 0, stream>>>(Wh1, wfWh1, 256, 256, 8, 65536);
    wpack_kernel<<<256, 256, 0, stream>>>(Wh2, wfWh2, 256, 256, 8, 65536);
    wpack_kernel<<<128, 256, 0, stream>>>(Wo,  wfWo,  256, 100, 4, 32768);
    bpack_kernel<<<4, 256, 0, stream>>>(bi, bh1, bh2, bo, biases);

    mlp_mfma_kernel<<<(int)(NROWS / 128), 256, 0, stream>>>(
        U, Wn, signs, wfWi, wfWh1, wfWh2, wfWo, biases, incr);
    y_kernel<<<B_SZ, 128, 0, stream>>>(incr, y0, yout);
}

// Round 10
// 315.700 us; speedup vs baseline: 2.0480x; 1.1965x over previous
//
#include <hip/hip_runtime.h>
#include <hip/hip_bf16.h>

typedef __hip_bfloat16 bf16;
typedef __attribute__((ext_vector_type(8)))  short bf16x8v;  // 8 bf16 (4 VGPRs) MFMA operand
typedef __attribute__((ext_vector_type(16))) float f32x16;   // 32x32 MFMA accumulator
typedef __attribute__((ext_vector_type(4)))  short short4v;  // 8B packed bf16 store

#define B_SZ   2048
#define NSTEP  128
#define DD     100
#define DX     100
#define DH     256

#define UCOLS  104          // 100 x-dims + t + 3 zero pad (global U layout)

__device__ __constant__ const float DT_   = 0.0078125f;              // 1/128
__device__ __constant__ const float SQDT_ = 0.08838834764831845f;    // sqrt(1/128)
// sqrt(2)*sqrt(dt) = sqrt(2/128) = 1/8 exactly
__device__ __constant__ const float C1_   = 0.125f;

// ---------------------------------------------------------------------------
// Kernel 1: per-batch prefix sums of noise -> build U rows (bf16) + final x
// U row p = (b*128 + i)*2 + h ; cols 0..99 = x-part, col 100 = t, 101..103 = 0
// ---------------------------------------------------------------------------
__global__ __launch_bounds__(128) void prep_kernel(
    const float* __restrict__ Wn, const int* __restrict__ signs,
    const float* __restrict__ x0,
    bf16* __restrict__ U, float* __restrict__ xout)
{
    __shared__ float w_l[DD * 129];   // padded stride 129 -> conflict-free
    __shared__ float s_l[NSTEP];
    const int b = blockIdx.x, tid = threadIdx.x;
    const float* wb = Wn + (size_t)b * DD * NSTEP;

    for (int idx = tid; idx < DD * NSTEP; idx += 128) {
        int d = idx >> 7, i = idx & 127;
        w_l[d * 129 + i] = wb[idx];
    }
    if (tid < NSTEP) s_l[tid] = 2.f * (float)signs[tid] - 1.f;
    __syncthreads();

    if (tid < DD) {
        const int d = tid;
        float x = x0[d];
        for (int i = 0; i < NSTEP; ++i) {
            size_t p = ((size_t)(b * NSTEP + i)) * 2;
            float wn = w_l[d * 129 + i];
            U[p * UCOLS + d]       = __float2bfloat16(x);
            U[(p + 1) * UCOLS + d] = __float2bfloat16(x + C1_ * (wn - s_l[i]));
            x += C1_ * wn;
        }
        xout[(size_t)b * DX + d] = x;   // exact f32 final x
    } else if (tid < UCOLS) {
        for (int i = 0; i < NSTEP; ++i) {
            size_t p = ((size_t)(b * NSTEP + i)) * 2;
            float v0 = 0.f, v1 = 0.f;
            if (tid == 100) { v0 = DT_ * (float)i; v1 = DT_ * (float)(i + 1); }
            U[p * UCOLS + tid]       = __float2bfloat16(v0);
            U[(p + 1) * UCOLS + tid] = __float2bfloat16(v1);
        }
    }
}

// ---------------------------------------------------------------------------
// Weight fragment packing for 32x32x16 MFMA (R7-proven):
// c-major: frag# = c*NTILE + t. elem idx = frag#*512 + lane*8 + j.
// n = t*32 + (lane&31), k = c*16 + (lane>>5)*8 + j. OOR -> 0.
// ---------------------------------------------------------------------------
__global__ __launch_bounds__(256) void wpack_kernel(
    const float* __restrict__ W, bf16* __restrict__ dst,
    int Kact, int Nact, int NTILE, int total)
{
    int idx = blockIdx.x * 256 + threadIdx.x;
    if (idx >= total) return;
    int j = idx & 7;
    int l = (idx >> 3) & 63;
    int frag = idx >> 9;
    int t = frag % NTILE;
    int c = frag / NTILE;
    int n = t * 32 + (l & 31);
    int k = c * 16 + (l >> 5) * 8 + j;
    float v = (k < Kact && n < Nact) ? W[(size_t)k * Nact + n] : 0.f;
    dst[idx] = __float2bfloat16(v);
}

// Pack biases into one padded f32 buffer: [0:256)=bi [256:512)=bh1 [512:768)=bh2 [768:896)=bo(pad0)
__global__ __launch_bounds__(256) void bpack_kernel(
    const float* __restrict__ bi, const float* __restrict__ bh1,
    const float* __restrict__ bh2, const float* __restrict__ bo,
    float* __restrict__ dst)
{
    int i = blockIdx.x * 256 + threadIdx.x;
    if (i < 256) dst[i] = bi[i];
    else if (i < 512) dst[i] = bh1[i - 256];
    else if (i < 768) dst[i] = bh2[i - 512];
    else if (i < 896) dst[i] = (i - 768 < DD) ? bo[i - 768] : 0.f;
}

// ---------------------------------------------------------------------------
// One 32x32x16-MFMA layer, IN PLACE, 64-row tile, 4-way n-split (R7 base)
// + 1-DEEP SOFTWARE PIPELINE on BOTH operands: loads for c+1 are issued
// before the MFMAs consuming c's registers, so the waitcnt before the MFMA
// cluster covers a full ~256-cyc MFMA phase instead of a raw L2 round-trip.
// Register cost: +16 arch (b-next 8, a-next 8) -> needs (256,3) cap 170.
// Wave w owns NT n-tiles at t0; all 64 rows (2 m-tiles of 32).
//   phase 1: pipelined accumulate -> __syncthreads
//   phase 2: bias+relu+pack, store back to buf
// Caller must __syncthreads() after return before the next layer reads.
// Swizzle: byte ^= (m&15)<<4 (R7-proven).
// ---------------------------------------------------------------------------
template<int KC, int NTT, int NT, bool RELU>
__device__ __forceinline__ void layer32(
    char* __restrict__ buf,
    const bf16* __restrict__ wfrag, const float* __restrict__ bias,
    int lane, int t0)
{
    const int mrow = lane & 31;   // m within tile (B col)
    const int kg   = lane >> 5;   // k-group (0/1)
    const int ma = mrow, mb = 32 + mrow;
    const int sa = (ma & 15) << 4, sb = (mb & 15) << 4;

    f32x16 acc[NT][2];
#pragma unroll
    for (int t = 0; t < NT; ++t)
#pragma unroll
        for (int mt = 0; mt < 2; ++mt)
#pragma unroll
            for (int e = 0; e < 16; ++e) acc[t][mt][e] = 0.f;

    const char* wptr = (const char*)wfrag + (size_t)t0 * 1024 + (size_t)lane * 16;

    // pipeline preload: c = 0
    bf16x8v bc0 = *(const bf16x8v*)(buf + ma * 512 + ((kg * 16) ^ sa));
    bf16x8v bc1 = *(const bf16x8v*)(buf + mb * 512 + ((kg * 16) ^ sb));
    bf16x8v ac[NT];
#pragma unroll
    for (int t = 0; t < NT; ++t)
        ac[t] = *(const bf16x8v*)(wptr + (size_t)t * 1024);

#pragma unroll
    for (int c = 0; c < KC; ++c) {
        const int cn = (c + 1 < KC) ? c + 1 : c;      // last iter: dummy reload
        const int ncol = cn * 32 + kg * 16;
        bf16x8v bn0 = *(const bf16x8v*)(buf + ma * 512 + (ncol ^ sa));
        bf16x8v bn1 = *(const bf16x8v*)(buf + mb * 512 + (ncol ^ sb));
        bf16x8v an[NT];
#pragma unroll
        for (int t = 0; t < NT; ++t)
            an[t] = *(const bf16x8v*)(wptr + (size_t)(cn * NTT + t) * 1024);

        __builtin_amdgcn_s_setprio(1);
#pragma unroll
        for (int t = 0; t < NT; ++t) {
            acc[t][0] = __builtin_amdgcn_mfma_f32_32x32x16_bf16(ac[t], bc0, acc[t][0], 0, 0, 0);
            acc[t][1] = __builtin_amdgcn_mfma_f32_32x32x16_bf16(ac[t], bc1, acc[t][1], 0, 0, 0);
        }
        __builtin_amdgcn_s_setprio(0);

        bc0 = bn0; bc1 = bn1;
#pragma unroll
        for (int t = 0; t < NT; ++t) ac[t] = an[t];
    }

    __syncthreads();   // all reads of buf complete block-wide; safe to overwrite

    // C/D layout 32x32: col(m) = lane&31, row(n) = (r&3) + 8*(r>>2) + 4*kg
#pragma unroll
    for (int t = 0; t < NT; ++t) {
#pragma unroll
        for (int g = 0; g < 4; ++g) {
            const int nb = (t0 + t) * 32 + g * 8 + kg * 4;  // 4 consecutive features
            const float4 bv = *(const float4*)(bias + nb);
#pragma unroll
            for (int mt = 0; mt < 2; ++mt) {
                const int m = mt * 32 + mrow;
                float v0 = acc[t][mt][g * 4 + 0] + bv.x;
                float v1 = acc[t][mt][g * 4 + 1] + bv.y;
                float v2 = acc[t][mt][g * 4 + 2] + bv.z;
                float v3 = acc[t][mt][g * 4 + 3] + bv.w;
                if (RELU) {
                    v0 = fmaxf(v0, 0.f); v1 = fmaxf(v1, 0.f);
                    v2 = fmaxf(v2, 0.f); v3 = fmaxf(v3, 0.f);
                }
                bf16 h0 = __float2bfloat16(v0), h1 = __float2bfloat16(v1);
                bf16 h2 = __float2bfloat16(v2), h3 = __float2bfloat16(v3);
                short4v pv;
                pv[0] = *(short*)&h0; pv[1] = *(short*)&h1;
                pv[2] = *(short*)&h2; pv[3] = *(short*)&h3;
                *(short4v*)(buf + m * 512 + ((nb * 2) ^ ((m & 15) << 4))) = pv;
            }
        }
    }
}

// ---------------------------------------------------------------------------
// Kernel 2: fused 4-layer 32x32-MFMA MLP over 64 rows + per-pair y-increment.
// R7 base + software pipeline. acc 64 AGPR + ~92 arch -> (256,3) cap 170,
// no spill expected (tripwire: WRITE_SIZE ~1MB / VGPR <= 106 arch).
// buf 32KB -> LDS 33280B; occupancy reg-capped at 3 blocks/CU (~37%).
// ---------------------------------------------------------------------------
__global__ __launch_bounds__(256, 3) void mlp_mfma_kernel(
    const bf16* __restrict__ U,
    const float* __restrict__ Wn, const int* __restrict__ signs,
    const bf16* __restrict__ wfWi, const bf16* __restrict__ wfWh1,
    const bf16* __restrict__ wfWh2, const bf16* __restrict__ wfWo,
    const float* __restrict__ biases, float* __restrict__ incr)
{
    __shared__ char buf[64 * 512];
    __shared__ float Sz2[64], Szw[64];
    const int tid = threadIdx.x;
    const int lane = tid & 63, w = tid >> 6;
    const size_t row0 = (size_t)blockIdx.x * 64;

    // Load U tile: 64 rows x 104 bf16 = 13 x 16B chunks/row -> buf [64][512B]
    // (layer-1 input occupies bytes 0..207, zero-fill to 255), swizzled.
    {
        const char* usrc = (const char*)(U + row0 * UCOLS);
        for (int idx = tid; idx < 1024; idx += 256) {
            int r = idx >> 4, c = idx & 15;
            uint4 v = (uint4){0, 0, 0, 0};
            if (c < 13) v = *(const uint4*)(usrc + r * 208 + c * 16);
            *(uint4*)(buf + r * 512 + ((c * 16) ^ ((r & 15) << 4))) = v;
        }
    }
    __syncthreads();

    layer32<7,  8, 2, true >(buf, wfWi,  biases,        lane, w * 2);
    __syncthreads();
    layer32<16, 8, 2, true >(buf, wfWh1, biases + 256,  lane, w * 2);
    __syncthreads();
    layer32<16, 8, 2, true >(buf, wfWh2, biases + 512,  lane, w * 2);
    __syncthreads();
    layer32<16, 4, 1, false>(buf, wfWo,  biases + 768,  lane, w);
    __syncthreads();
    // z rows now in buf [64][512B] (features 0..99 valid)

    // Per-row reductions: 4 threads per row
    const int r = tid >> 2, q = tid & 3;
    const size_t g = row0 + r;
    const size_t pair = g >> 1;
    const int h = (int)(g & 1);
    const int bb = (int)(pair >> 7), ii = (int)(pair & 127);
    const float s = 2.f * (float)signs[ii] - 1.f;
    const float sdt = s * SQDT_;
    const float* wb = Wn + (size_t)bb * DD * NSTEP + ii;

    float sz2 = 0.f, szw = 0.f;
    for (int d = q; d < DD; d += 4) {
        unsigned short zb = *(const unsigned short*)(buf + r * 512 + ((d * 2) ^ ((r & 15) << 4)));
        union { unsigned int u; float f; } cv; cv.u = ((unsigned int)zb) << 16;
        float z = cv.f;
        float wv = SQDT_ * wb[(size_t)d * NSTEP];
        float wt = h ? (wv + sdt) : (wv - sdt);
        sz2 += z * z;
        szw += z * wt;
    }
    sz2 += __shfl_xor(sz2, 1); sz2 += __shfl_xor(sz2, 2);
    szw += __shfl_xor(szw, 1); szw += __shfl_xor(szw, 2);
    if (q == 0) { Sz2[r] = sz2; Szw[r] = szw; }
    __syncthreads();

    // incr = -||z||^2*dt + 0.5*(z.(w-sdt) + z_new.(w+sdt));  z from h=0 row
    if (tid < 32) {
        int rr = tid * 2;
        incr[row0 / 2 + tid] = -Sz2[rr] * DT_ + 0.5f * (Szw[rr] + Szw[rr + 1]);
    }
}

// ---------------------------------------------------------------------------
// Kernel 3: y[b] = y0 + sum_i incr[b*128+i]
// ---------------------------------------------------------------------------
__global__ __launch_bounds__(128) void y_kernel(
    const float* __restrict__ incr, const float* __restrict__ y0,
    float* __restrict__ yout)
{
    const int b = blockIdx.x, tid = threadIdx.x;
    float v = incr[(size_t)b * NSTEP + tid];
#pragma unroll
    for (int off = 1; off < 64; off <<= 1) v += __shfl_xor(v, off);
    __shared__ float partial[2];
    if ((tid & 63) == 0) partial[tid >> 6] = v;
    __syncthreads();
    if (tid == 0) yout[b] = y0[0] + partial[0] + partial[1];
}

// ---------------------------------------------------------------------------
extern "C" void kernel_launch(void* const* d_in, const int* in_sizes, int n_in,
                              void* d_out, int out_size, void* d_ws, size_t ws_size,
                              hipStream_t stream) {
    (void)in_sizes; (void)n_in; (void)out_size; (void)ws_size;
    const float* Wn    = (const float*)d_in[0];
    const int*   signs = (const int*)d_in[1];
    const float* x0    = (const float*)d_in[2];
    const float* y0    = (const float*)d_in[3];
    const float* Wi    = (const float*)d_in[4];
    const float* bi    = (const float*)d_in[5];
    const float* Wh1   = (const float*)d_in[6];
    const float* bh1   = (const float*)d_in[7];
    const float* Wh2   = (const float*)d_in[8];
    const float* bh2   = (const float*)d_in[9];
    const float* Wo    = (const float*)d_in[10];
    const float* bo    = (const float*)d_in[11];

    float* out  = (float*)d_out;
    float* xout = out;                       // [2048,100]
    float* yout = out + (size_t)B_SZ * DX;   // [2048,1]

    const size_t NROWS = (size_t)B_SZ * NSTEP * 2;           // 524288
    char* ws = (char*)d_ws;
    size_t off = 0;
    bf16*  U      = (bf16*)(ws + off); off += NROWS * UCOLS * sizeof(bf16);   // ~109 MB
    float* incr   = (float*)(ws + off); off += (NROWS / 2) * sizeof(float);   // 1 MB
    bf16*  wfWi   = (bf16*)(ws + off); off += 28672 * sizeof(bf16);   // KC=7,  8 tiles
    bf16*  wfWh1  = (bf16*)(ws + off); off += 65536 * sizeof(bf16);   // KC=16, 8 tiles
    bf16*  wfWh2  = (bf16*)(ws + off); off += 65536 * sizeof(bf16);
    bf16*  wfWo   = (bf16*)(ws + off); off += 32768 * sizeof(bf16);   // KC=16, 4 tiles
    float* biases = (float*)(ws + off); off += 896 * sizeof(float);

    prep_kernel<<<B_SZ, 128, 0, stream>>>(Wn, signs, x0, U, xout);
    // c-major 32x32 frag layout: NTILE = n-tiles of 32
    wpack_kernel<<<112, 256, 0, stream>>>(Wi,  wfWi,  101, 256, 8, 28672);
    wpack_kernel<<<256, 256, 0, stream>>>(Wh1, wfWh1, 256, 256, 8, 65536);
    wpack_kernel<<<256, 256, 0, stream>>>(Wh2, wfWh2, 256, 256, 8, 65536);
    wpack_kernel<<<128, 256, 0, stream>>>(Wo,  wfWo,  256, 100, 4, 32768);
    bpack_kernel<<<4, 256, 0, stream>>>(bi, bh1, bh2, bo, biases);

    mlp_mfma_kernel<<<(int)(NROWS / 64), 256, 0, stream>>>(
        U, Wn, signs, wfWi, wfWh1, wfWh2, wfWo, biases, incr);
    y_kernel<<<B_SZ, 128, 0, stream>>>(incr, y0, yout);
}